// Round 1
// baseline (471.119 us; speedup 1.0000x reference)
//
#include <hip/hip_runtime.h>

#define N_ROWS 16384
#define N_COLS 4096
#define MARGIN 0.1f
#define BLOCK  256
#define NBLK   2048                        // 8 blocks/CU on 256 CUs
#define ROWS_PER_BLK (N_ROWS / NBLK)       // 8 rows per block
#define V4_PER_ROW (N_COLS / 4)            // 1024 vec4 per row
#define K_LOADS (V4_PER_ROW / BLOCK)       // 4 vec4 per thread per row

typedef float vf4 __attribute__((ext_vector_type(4)));
typedef int   vi4 __attribute__((ext_vector_type(4)));

// Fused single-pass kernel. Each block owns ROWS_PER_BLK consecutive rows.
// Per row: stream the cossim slice AND the target slice together (both
// nontemporal -- zero reuse), form the correct-column sim via a one-hot dot
// product kept in registers, broadcast it with one wave-shfl reduce + one
// LDS exchange + one __syncthreads, then compute the hinge from the cossim
// values still sitting in registers. cossim is read exactly once from HBM;
// no cs_table, no second kernel, no cross-kernel dependency.
//
// The correct column contributes max(m + s - s, 0) = MARGIN per row; the
// final reduce subtracts it once globally: loss = sum/N - MARGIN.
__global__ __launch_bounds__(BLOCK) void
mm_fused_kernel(const float* __restrict__ cossim,
                const int* __restrict__ target,
                float* __restrict__ partials) {
    const vf4* __restrict__ c4 = (const vf4*)cossim;
    const vi4* __restrict__ t4 = (const vi4*)target;

    __shared__ float s_wave[2][BLOCK / 64];   // parity-buffered: 1 sync/row
    const int lane = threadIdx.x & 63, wave = threadIdx.x >> 6;

    float acc = 0.0f;
    const unsigned row0 = blockIdx.x * ROWS_PER_BLK;

#pragma unroll
    for (int r = 0; r < ROWS_PER_BLK; ++r) {
        const unsigned rbase = (row0 + r) * V4_PER_ROW + threadIdx.x;

        vf4 c[K_LOADS];
#pragma unroll
        for (int k = 0; k < K_LOADS; ++k)
            c[k] = __builtin_nontemporal_load(&c4[rbase + k * BLOCK]);
        vi4 t[K_LOADS];
#pragma unroll
        for (int k = 0; k < K_LOADS; ++k)
            t[k] = __builtin_nontemporal_load(&t4[rbase + k * BLOCK]);

        // One-hot dot: exactly one lane/element is nonzero across the row.
        float s = 0.0f;
#pragma unroll
        for (int k = 0; k < K_LOADS; ++k)
#pragma unroll
            for (int j = 0; j < 4; ++j)
                s += (t[k][j] != 0) ? c[k][j] : 0.0f;

#pragma unroll
        for (int off = 32; off > 0; off >>= 1)
            s += __shfl_down(s, off, 64);
        if (lane == 0) s_wave[r & 1][wave] = s;
        __syncthreads();
        const float srow = s_wave[r & 1][0] + s_wave[r & 1][1]
                         + s_wave[r & 1][2] + s_wave[r & 1][3];

        const float mc = MARGIN - srow;
#pragma unroll
        for (int k = 0; k < K_LOADS; ++k)
#pragma unroll
            for (int j = 0; j < 4; ++j)
                acc += fmaxf(mc + c[k][j], 0.0f);
    }

    // Block-level reduction of the hinge partial.
#pragma unroll
    for (int off = 32; off > 0; off >>= 1)
        acc += __shfl_down(acc, off, 64);
    __shared__ float s_acc[BLOCK / 64];
    if (lane == 0) s_acc[wave] = acc;
    __syncthreads();
    if (threadIdx.x == 0)
        partials[blockIdx.x] = s_acc[0] + s_acc[1] + s_acc[2] + s_acc[3];
}

// Final reduce over NBLK partials. loss = sum/N - MARGIN.
__global__ __launch_bounds__(BLOCK) void
mm_reduce_kernel(const float* __restrict__ partials, float* __restrict__ out) {
    const int t = threadIdx.x;
    float acc = 0.0f;
    for (int i = t; i < NBLK; i += BLOCK) acc += partials[i];
#pragma unroll
    for (int off = 32; off > 0; off >>= 1)
        acc += __shfl_down(acc, off, 64);
    __shared__ float s_wave[BLOCK / 64];
    const int lane = t & 63, wave = t >> 6;
    if (lane == 0) s_wave[wave] = acc;
    __syncthreads();
    if (t == 0)
        out[0] = (s_wave[0] + s_wave[1] + s_wave[2] + s_wave[3]) * (1.0f / N_ROWS)
                 - MARGIN;
}

extern "C" void kernel_launch(void* const* d_in, const int* in_sizes, int n_in,
                              void* d_out, int out_size, void* d_ws, size_t ws_size,
                              hipStream_t stream) {
    const float* cossim = (const float*)d_in[0];
    const int*   target = (const int*)d_in[1];
    float* out      = (float*)d_out;
    float* partials = (float*)d_ws;                  // NBLK floats

    mm_fused_kernel<<<NBLK, BLOCK, 0, stream>>>(cossim, target, partials);
    mm_reduce_kernel<<<1, BLOCK, 0, stream>>>(partials, out);
}

// Round 2
// 466.726 us; speedup vs baseline: 1.0094x; 1.0094x over previous
//
#include <hip/hip_runtime.h>

#define N_ROWS 16384
#define N_COLS 4096
#define MARGIN 0.1f
#define BLOCK  256
#define WAVES_PER_BLK (BLOCK / 64)                       // 4
#define ROWS_PER_WAVE 2
#define NBLK   (N_ROWS / (WAVES_PER_BLK * ROWS_PER_WAVE)) // 2048 (8 blocks/CU)
#define V4_PER_ROW (N_COLS / 4)                          // 1024 vec4 per row
#define K_LOADS (V4_PER_ROW / 64)                        // 16 vec4 per lane per row

typedef float vf4 __attribute__((ext_vector_type(4)));
typedef int   vi4 __attribute__((ext_vector_type(4)));

// Wave-private rows: one wave owns a full 4096-col row (64 lanes x 16 vec4).
// The row's cossim slice lives in 64 VGPRs; target streams through in groups
// of 4 vec4 and is consumed into the one-hot dot product s. The row-sum
// broadcast is 6 shfl_xor ops -- NO LDS, NO __syncthreads in the main loop,
// so waves drift freely and keep ~32 16B loads in flight each. The hinge is
// then computed from the registers already holding cossim: each input byte
// is read from HBM exactly once, nontemporally (zero reuse, don't pollute L2).
//
// The correct column contributes max(m + s - s, 0) = MARGIN per row; the
// final reduce subtracts it once globally: loss = sum/N - MARGIN.
__global__ __launch_bounds__(BLOCK, 4) void
mm_fused_kernel(const float* __restrict__ cossim,
                const int* __restrict__ target,
                float* __restrict__ partials) {
    const vf4* __restrict__ c4 = (const vf4*)cossim;
    const vi4* __restrict__ t4 = (const vi4*)target;
    const int lane = threadIdx.x & 63, wave = threadIdx.x >> 6;
    const unsigned gwave = blockIdx.x * WAVES_PER_BLK + wave;

    float acc = 0.0f;
#pragma unroll
    for (int r = 0; r < ROWS_PER_WAVE; ++r) {
        const unsigned row  = gwave * ROWS_PER_WAVE + r;
        const unsigned base = row * V4_PER_ROW + lane;

        // Issue the full row of cossim loads first (held for the hinge pass).
        vf4 c[K_LOADS];
#pragma unroll
        for (int k = 0; k < K_LOADS; ++k)
            c[k] = __builtin_nontemporal_load(&c4[base + k * 64]);

        // Stream target in groups of 4 vec4; consume into the one-hot dot.
        float s = 0.0f;
#pragma unroll
        for (int g = 0; g < K_LOADS / 4; ++g) {
            vi4 t[4];
#pragma unroll
            for (int u = 0; u < 4; ++u)
                t[u] = __builtin_nontemporal_load(&t4[base + (g * 4 + u) * 64]);
#pragma unroll
            for (int u = 0; u < 4; ++u)
#pragma unroll
                for (int j = 0; j < 4; ++j)
                    s += (t[u][j] != 0) ? c[g * 4 + u][j] : 0.0f;
        }

        // Wave-wide butterfly: all 64 lanes end with the row sum. No LDS.
#pragma unroll
        for (int off = 1; off < 64; off <<= 1)
            s += __shfl_xor(s, off, 64);

        const float mc = MARGIN - s;
#pragma unroll
        for (int k = 0; k < K_LOADS; ++k)
#pragma unroll
            for (int j = 0; j < 4; ++j)
                acc += fmaxf(mc + c[k][j], 0.0f);
    }

    // Single block-level reduction at the end (only sync in the kernel).
#pragma unroll
    for (int off = 32; off > 0; off >>= 1)
        acc += __shfl_down(acc, off, 64);
    __shared__ float s_acc[WAVES_PER_BLK];
    if (lane == 0) s_acc[wave] = acc;
    __syncthreads();
    if (threadIdx.x == 0)
        partials[blockIdx.x] = s_acc[0] + s_acc[1] + s_acc[2] + s_acc[3];
}

// Final reduce over NBLK partials. loss = sum/N - MARGIN.
__global__ __launch_bounds__(BLOCK) void
mm_reduce_kernel(const float* __restrict__ partials, float* __restrict__ out) {
    const int t = threadIdx.x;
    float acc = 0.0f;
    for (int i = t; i < NBLK; i += BLOCK) acc += partials[i];
#pragma unroll
    for (int off = 32; off > 0; off >>= 1)
        acc += __shfl_down(acc, off, 64);
    __shared__ float s_wave[BLOCK / 64];
    const int lane = t & 63, wave = t >> 6;
    if (lane == 0) s_wave[wave] = acc;
    __syncthreads();
    if (t == 0)
        out[0] = (s_wave[0] + s_wave[1] + s_wave[2] + s_wave[3]) * (1.0f / N_ROWS)
                 - MARGIN;
}

extern "C" void kernel_launch(void* const* d_in, const int* in_sizes, int n_in,
                              void* d_out, int out_size, void* d_ws, size_t ws_size,
                              hipStream_t stream) {
    const float* cossim = (const float*)d_in[0];
    const int*   target = (const int*)d_in[1];
    float* out      = (float*)d_out;
    float* partials = (float*)d_ws;                  // NBLK floats

    mm_fused_kernel<<<NBLK, BLOCK, 0, stream>>>(cossim, target, partials);
    mm_reduce_kernel<<<1, BLOCK, 0, stream>>>(partials, out);
}